// Round 10
// baseline (163.552 us; speedup 1.0000x reference)
//
#include <hip/hip_runtime.h>
#include <hip/hip_bf16.h>

#define B 32
#define C 512
#define HW 3136            // 56*56 floats per plane
#define HW4 784            // fx4 per plane
#define TH 0.01f
#define NPG 32             // partial groups (blocks per batch) in kernel A
#define CPB 16             // channels per block in kernel A
#define FX4_PER_B (C * HW4)              // 401408 fx4 per batch in out
#define BLK_B 56                         // kernel-B blocks per batch (32*56=1792 = 7.0/CU)
#define FX4_PER_BLK (FX4_PER_B / BLK_B)  // 7168
#define ITERS (FX4_PER_BLK / 256)        // 28

typedef float fx4 __attribute__((ext_vector_type(4)));

// ---------------------------------------------------------------------------
// Kernel A: single-pass partial saliency (R9 structure) + last-block-per-b
// reduction of the 32 partial planes into sal[b] (d_ws).
// Block = (b, pg) owns 16 channels; each wave owns fx4-cols [196w, 196w+196)
// of every channel. Per 2-channel group: load quarters (cached), in-wave
// reduce -> plane sums, 16-float LDS exchange (parity, 1 barrier), alphas,
// FMA into per-wave acc. Waves store disjoint quarters of the partial plane
// (d_out plane pg of batch b). The 32nd finishing block of each b then sums
// the 32 partials in FIXED order -> sal[b] (deterministic).
// ---------------------------------------------------------------------------
__global__ __launch_bounds__(256, 4) void partial_kernel(const float* __restrict__ x,
                                                         float* __restrict__ out,
                                                         float* __restrict__ sal,
                                                         int* __restrict__ cnt) {
    const int b  = blockIdx.y;
    const int pg = blockIdx.x;          // 0..NPG-1
    const int t  = threadIdx.x;
    const int l  = t & 63;
    const int wv = t >> 6;

    __shared__ float sums[2][2][4];     // [parity][channel][wave]
    __shared__ int sh_last;

    const float* __restrict__ xb = x + (size_t)b * C * HW;
    const int qbase = wv * 196;         // this wave's fx4-col base

    fx4 acc0 = (fx4)0.f, acc1 = (fx4)0.f, acc2 = (fx4)0.f, acc3 = (fx4)0.f;

    #pragma unroll 2
    for (int g = 0; g < 8; ++g) {
        const int c0 = pg * CPB + 2 * g;
        const fx4* __restrict__ p0 = (const fx4*)(xb + (size_t)c0 * HW) + qbase + l;
        const fx4* __restrict__ p1 = (const fx4*)(xb + (size_t)(c0 + 1) * HW) + qbase + l;

        const fx4 a0 = p0[0], a1 = p0[64], a2 = p0[128];
        const fx4 b0 = p1[0], b1 = p1[64], b2 = p1[128];
        fx4 a3 = (fx4)0.f, b3 = (fx4)0.f;
        if (l < 4) { a3 = p0[192]; b3 = p1[192]; }

        float sa = (((a0.x + a0.y) + (a0.z + a0.w)) + ((a1.x + a1.y) + (a1.z + a1.w))) +
                   (((a2.x + a2.y) + (a2.z + a2.w)) + ((a3.x + a3.y) + (a3.z + a3.w)));
        float sb = (((b0.x + b0.y) + (b0.z + b0.w)) + ((b1.x + b1.y) + (b1.z + b1.w))) +
                   (((b2.x + b2.y) + (b2.z + b2.w)) + ((b3.x + b3.y) + (b3.z + b3.w)));
        #pragma unroll
        for (int off = 1; off < 64; off <<= 1) {
            sa += __shfl_xor(sa, off);
            sb += __shfl_xor(sb, off);
        }
        if (l == 0) {
            sums[g & 1][0][wv] = sa;
            sums[g & 1][1][wv] = sb;
        }
        __syncthreads();
        const float al0 = ((sums[g & 1][0][0] + sums[g & 1][0][1]) +
                           (sums[g & 1][0][2] + sums[g & 1][0][3])) * (1.0f / (float)HW);
        const float al1 = ((sums[g & 1][1][0] + sums[g & 1][1][1]) +
                           (sums[g & 1][1][2] + sums[g & 1][1][3])) * (1.0f / (float)HW);

        acc0 += a0 * al0 + b0 * al1;
        acc1 += a1 * al0 + b1 * al1;
        acc2 += a2 * al0 + b2 * al1;
        acc3 += a3 * al0 + b3 * al1;
    }

    // disjoint store of this wave's quarter of the partial plane (cached)
    fx4* __restrict__ dst = (fx4*)(out + (size_t)b * C * HW + (size_t)pg * HW) + qbase + l;
    dst[0]   = acc0;
    dst[64]  = acc1;
    dst[128] = acc2;
    if (l < 4) dst[192] = acc3;

    // ---- last-block-per-b: reduce 32 partial planes -> sal[b] -------------
    __syncthreads();                    // drains vmem before barrier (compiler waitcnt)
    if (t == 0) {
        __threadfence();                // agent-scope release of this block's stores
        const int old = __hip_atomic_fetch_add(&cnt[b], 1, __ATOMIC_ACQ_REL,
                                               __HIP_MEMORY_SCOPE_AGENT);
        sh_last = (old == NPG - 1);
    }
    __syncthreads();
    if (!sh_last) return;

    const fx4* __restrict__ Pb = (const fx4*)(out + (size_t)b * C * HW);
    fx4* __restrict__ salv = (fx4*)(sal + (size_t)b * HW);
    for (int i = t; i < HW4; i += 256) {
        fx4 s = (fx4)0.f;
        #pragma unroll
        for (int g = 0; g < NPG; ++g) s += Pb[(size_t)g * HW4 + i];
        salv[i] = s * (1.0f / (float)C);
    }
}

// ---------------------------------------------------------------------------
// Kernel B: pure streaming expansion, perfectly balanced.
// 1792 blocks (56/b) = exactly 7 blocks/CU; each block owns a contiguous
// 7168-fx4 range of out[b]: 28 iters x 256 threads of contiguous NT stores.
// sal[b] (12.5 KB) + w (2 KB) staged in LDS; col/co tracked incrementally.
// ---------------------------------------------------------------------------
__global__ __launch_bounds__(256) void out_kernel(const fx4* __restrict__ sal,
                                                  const float* __restrict__ w,
                                                  const float* __restrict__ scale_p,
                                                  const float* __restrict__ wf_p,
                                                  float* __restrict__ out) {
    const int bid = blockIdx.x;
    const int b   = bid / BLK_B;
    const int j   = bid % BLK_B;
    const int t   = threadIdx.x;

    __shared__ fx4  sal_sm[HW4];               // 12,544 B
    __shared__ float w_sm[C];                  //  2,048 B
    const fx4* __restrict__ sb = sal + (size_t)b * HW4;
    for (int i = t; i < HW4; i += 256) sal_sm[i] = sb[i];
    for (int i = t; i < C;   i += 256) w_sm[i]  = w[i];
    __syncthreads();

    const float scale = scale_p[0];
    const float wf    = wf_p[0];
    const float z     = 1.0f - 0.5f * wf;      // fm == 0 path

    const int F0 = j * FX4_PER_BLK;
    fx4* __restrict__ ob = (fx4*)(out + (size_t)b * C * HW) + F0;

    int colb = F0 % HW4;                       // uniform per block
    int cob  = F0 / HW4;

    for (int it = 0; it < ITERS; ++it) {
        int c = colb + t;                      // < 784+256: wraps at most once
        const int wrapped = (c >= HW4) ? 1 : 0;
        c -= wrapped ? HW4 : 0;
        const fx4  s4 = sal_sm[c];
        const float wc = w_sm[cob + wrapped];

        fx4 r;
        float fm;
        fm = s4.x * wc;
        r.x = (fm > TH) ? 1.0f - wf / (1.0f + __expf(-scale * fm)) : z;
        fm = s4.y * wc;
        r.y = (fm > TH) ? 1.0f - wf / (1.0f + __expf(-scale * fm)) : z;
        fm = s4.z * wc;
        r.z = (fm > TH) ? 1.0f - wf / (1.0f + __expf(-scale * fm)) : z;
        fm = s4.w * wc;
        r.w = (fm > TH) ? 1.0f - wf / (1.0f + __expf(-scale * fm)) : z;
        __builtin_nontemporal_store(r, ob + it * 256 + t);

        colb += 256;
        if (colb >= HW4) { colb -= HW4; ++cob; }
    }
}

extern "C" void kernel_launch(void* const* d_in, const int* in_sizes, int n_in,
                              void* d_out, int out_size, void* d_ws, size_t ws_size,
                              hipStream_t stream) {
    const float* x      = (const float*)d_in[0];
    const float* conv_w = (const float*)d_in[1];   // 512 floats
    const float* scale  = (const float*)d_in[2];
    const float* wf     = (const float*)d_in[3];
    float* out = (float*)d_out;
    float* sal = (float*)d_ws;                             // B*HW floats = 401,408 B
    int*   cnt = (int*)((char*)d_ws + (size_t)B * HW * 4); // 32 ints

    hipMemsetAsync(cnt, 0, B * sizeof(int), stream);

    dim3 gridA(NPG, B);                            // 32 x 32 = 1024 blocks
    partial_kernel<<<gridA, 256, 0, stream>>>(x, out, sal, cnt);

    out_kernel<<<B * BLK_B, 256, 0, stream>>>((const fx4*)sal, conv_w, scale, wf, out);
}

// Round 11
// 147.725 us; speedup vs baseline: 1.1071x; 1.1071x over previous
//
#include <hip/hip_runtime.h>
#include <hip/hip_bf16.h>

#define B 32
#define C 512
#define HW 3136            // 56*56 floats per plane
#define HW4 784            // fx4 per plane
#define TH 0.01f
#define NPG 64             // partial groups (blocks per batch)
#define CPB 8              // channels per block

typedef float fx4 __attribute__((ext_vector_type(4)));

// ---------------------------------------------------------------------------
// Kernel A: single-pass partial saliency, quarter-plane per wave.
// Block = (b, pg) owns 8 channels. Grid 64 x 32 = 2048 blocks = 8/CU
// (32 waves/CU) for maximum memory-level parallelism - R9 showed A is
// latency-bound at 4 blocks/CU. Each wave owns fx4-cols [196w, 196w+196)
// of every channel; per 2-channel group: cached loads, in-wave tree+shfl
// reduce -> plane sums, 16-float LDS exchange (parity, 1 barrier), alphas,
// FMA into per-wave acc (4 fx4). Waves store disjoint quarters of the
// partial plane (d_out plane pg). No fences, no atomics (R10 lesson).
// ---------------------------------------------------------------------------
__global__ __launch_bounds__(256, 8) void partial_kernel(const float* __restrict__ x,
                                                         float* __restrict__ out) {
    const int b  = blockIdx.y;
    const int pg = blockIdx.x;          // 0..NPG-1
    const int t  = threadIdx.x;
    const int l  = t & 63;
    const int wv = t >> 6;

    __shared__ float sums[2][2][4];     // [parity][channel][wave]

    const float* __restrict__ xb = x + (size_t)b * C * HW;
    const int qbase = wv * 196;         // this wave's fx4-col base

    fx4 acc0 = (fx4)0.f, acc1 = (fx4)0.f, acc2 = (fx4)0.f, acc3 = (fx4)0.f;

    #pragma unroll 2
    for (int g = 0; g < 4; ++g) {
        const int c0 = pg * CPB + 2 * g;
        const fx4* __restrict__ p0 = (const fx4*)(xb + (size_t)c0 * HW) + qbase + l;
        const fx4* __restrict__ p1 = (const fx4*)(xb + (size_t)(c0 + 1) * HW) + qbase + l;

        const fx4 a0 = p0[0], a1 = p0[64], a2 = p0[128];
        const fx4 b0 = p1[0], b1 = p1[64], b2 = p1[128];
        fx4 a3 = (fx4)0.f, b3 = (fx4)0.f;
        if (l < 4) { a3 = p0[192]; b3 = p1[192]; }

        float sa = (((a0.x + a0.y) + (a0.z + a0.w)) + ((a1.x + a1.y) + (a1.z + a1.w))) +
                   (((a2.x + a2.y) + (a2.z + a2.w)) + ((a3.x + a3.y) + (a3.z + a3.w)));
        float sb = (((b0.x + b0.y) + (b0.z + b0.w)) + ((b1.x + b1.y) + (b1.z + b1.w))) +
                   (((b2.x + b2.y) + (b2.z + b2.w)) + ((b3.x + b3.y) + (b3.z + b3.w)));
        #pragma unroll
        for (int off = 1; off < 64; off <<= 1) {
            sa += __shfl_xor(sa, off);
            sb += __shfl_xor(sb, off);
        }
        if (l == 0) {
            sums[g & 1][0][wv] = sa;
            sums[g & 1][1][wv] = sb;
        }
        __syncthreads();
        const float al0 = ((sums[g & 1][0][0] + sums[g & 1][0][1]) +
                           (sums[g & 1][0][2] + sums[g & 1][0][3])) * (1.0f / (float)HW);
        const float al1 = ((sums[g & 1][1][0] + sums[g & 1][1][1]) +
                           (sums[g & 1][1][2] + sums[g & 1][1][3])) * (1.0f / (float)HW);

        acc0 += a0 * al0 + b0 * al1;
        acc1 += a1 * al0 + b1 * al1;
        acc2 += a2 * al0 + b2 * al1;
        acc3 += a3 * al0 + b3 * al1;
    }

    // direct disjoint store of this wave's quarter (cached; B re-reads it)
    fx4* __restrict__ dst = (fx4*)(out + (size_t)b * C * HW + (size_t)pg * HW) + qbase + l;
    dst[0]   = acc0;
    dst[64]  = acc1;
    dst[128] = acc2;
    if (l < 4) dst[192] = acc3;
}

// ---------------------------------------------------------------------------
// Kernel B: sum 64 partials -> sal, then expansion (R9 structure).
// Block = (b, tile of 16 fx4 cols). Partials live in d_out planes co=0..63,
// read before this block overwrites them (read->sync->write within block).
// ---------------------------------------------------------------------------
__global__ __launch_bounds__(256) void out_kernel(const float* __restrict__ w,
                                                  const float* __restrict__ scale_p,
                                                  const float* __restrict__ wf_p,
                                                  float* __restrict__ out) {
    const int b    = blockIdx.y;
    const int tile = blockIdx.x;               // 0..48
    const int t    = threadIdx.x;
    const int hw4  = t & 15;
    const int pg4  = t >> 4;                   // 0..15 -> partials 4*pg4 .. 4*pg4+3
    const int lane = t & 63;
    const int wid  = t >> 6;

    const fx4* __restrict__ P =
        (const fx4*)(out + (size_t)b * C * HW) + tile * 16 + hw4;
    fx4 s = (P[(size_t)(4 * pg4) * HW4]     + P[(size_t)(4 * pg4 + 1) * HW4]) +
            (P[(size_t)(4 * pg4 + 2) * HW4] + P[(size_t)(4 * pg4 + 3) * HW4]);

    // reduce the 4 pg4-groups in this wave (lane deltas 16, 32)
    s.x += __shfl_xor(s.x, 16); s.y += __shfl_xor(s.y, 16);
    s.z += __shfl_xor(s.z, 16); s.w += __shfl_xor(s.w, 16);
    s.x += __shfl_xor(s.x, 32); s.y += __shfl_xor(s.y, 32);
    s.z += __shfl_xor(s.z, 32); s.w += __shfl_xor(s.w, 32);

    __shared__ fx4 red[4][16];
    if (lane < 16) red[wid][lane] = s;
    __syncthreads();

    __shared__ fx4 sal_sm[16];
    if (t < 16) {
        sal_sm[t] = ((red[0][t] + red[1][t]) + (red[2][t] + red[3][t])) *
                    (1.0f / (float)C);
    }
    __syncthreads();

    const float scale = scale_p[0];
    const float wf    = wf_p[0];
    const float out_zero = 1.0f - 0.5f * wf;   // fm == 0 path
    const fx4 s4 = sal_sm[hw4];

    fx4* __restrict__ ob = (fx4*)(out + (size_t)b * C * HW) + tile * 16 + hw4;
    const int c0 = pg4 * 32;                   // each group covers its 32 co's

    #pragma unroll 4
    for (int k = 0; k < 32; ++k) {
        const int co = c0 + k;
        const float wc = w[co];
        fx4 r;
        float fm;
        fm = s4.x * wc;
        r.x = (fm > TH) ? 1.0f - wf / (1.0f + __expf(-scale * fm)) : out_zero;
        fm = s4.y * wc;
        r.y = (fm > TH) ? 1.0f - wf / (1.0f + __expf(-scale * fm)) : out_zero;
        fm = s4.z * wc;
        r.z = (fm > TH) ? 1.0f - wf / (1.0f + __expf(-scale * fm)) : out_zero;
        fm = s4.w * wc;
        r.w = (fm > TH) ? 1.0f - wf / (1.0f + __expf(-scale * fm)) : out_zero;
        __builtin_nontemporal_store(r, ob + (size_t)co * HW4);
    }
}

extern "C" void kernel_launch(void* const* d_in, const int* in_sizes, int n_in,
                              void* d_out, int out_size, void* d_ws, size_t ws_size,
                              hipStream_t stream) {
    const float* x      = (const float*)d_in[0];
    const float* conv_w = (const float*)d_in[1];   // 512 floats
    const float* scale  = (const float*)d_in[2];
    const float* wf     = (const float*)d_in[3];
    float* out = (float*)d_out;

    dim3 gridA(NPG, B);                            // 64 x 32 = 2048 blocks
    partial_kernel<<<gridA, 256, 0, stream>>>(x, out);

    dim3 gridB(HW4 / 16, B);                       // 49 x 32 = 1568 blocks
    out_kernel<<<gridB, 256, 0, stream>>>(conv_w, scale, wf, out);
}

// Round 12
// 83.366 us; speedup vs baseline: 1.9619x; 1.7720x over previous
//
#include <hip/hip_runtime.h>
#include <hip/hip_bf16.h>

#define B 32
#define C 512
#define HW 3136            // 56*56 floats per plane
#define HW4 784            // fx4 per plane
#define TH 0.01f
#define NPG 64             // partial groups (blocks per batch)
#define CPB 8              // channels per block

typedef float fx4 __attribute__((ext_vector_type(4)));

// ---------------------------------------------------------------------------
// Kernel A: single-pass partial saliency, quarter-plane per wave.
// Block = (b, pg) owns 8 channels. Grid 64 x 32 = 2048 blocks.
// __launch_bounds__(256,4): cap 128 VGPR. Natural usage ~64 VGPR (measured
// 64 in R10 for the same inner structure) -> HW allows 8 blocks/CU = 32
// waves/CU; 2048 blocks fill that. DO NOT use (256,8): R11 showed the
// compiler then targets 32 VGPR and spills everything to scratch
// (WRITE_SIZE 180 MB of spill traffic, A: 45 -> 126 us).
// Each wave owns fx4-cols [196w, 196w+196) of every channel; per 2-channel
// group: cached loads, in-wave tree+shfl reduce -> plane sums, 16-float LDS
// exchange (parity, 1 barrier), alphas, FMA into per-wave acc (4 fx4).
// Waves store disjoint quarters of the partial plane (d_out plane pg).
// No fences, no atomics (R10 lesson).
// ---------------------------------------------------------------------------
__global__ __launch_bounds__(256, 4) void partial_kernel(const float* __restrict__ x,
                                                         float* __restrict__ out) {
    const int b  = blockIdx.y;
    const int pg = blockIdx.x;          // 0..NPG-1
    const int t  = threadIdx.x;
    const int l  = t & 63;
    const int wv = t >> 6;

    __shared__ float sums[2][2][4];     // [parity][channel][wave]

    const float* __restrict__ xb = x + (size_t)b * C * HW;
    const int qbase = wv * 196;         // this wave's fx4-col base

    fx4 acc0 = (fx4)0.f, acc1 = (fx4)0.f, acc2 = (fx4)0.f, acc3 = (fx4)0.f;

    #pragma unroll 2
    for (int g = 0; g < 4; ++g) {
        const int c0 = pg * CPB + 2 * g;
        const fx4* __restrict__ p0 = (const fx4*)(xb + (size_t)c0 * HW) + qbase + l;
        const fx4* __restrict__ p1 = (const fx4*)(xb + (size_t)(c0 + 1) * HW) + qbase + l;

        const fx4 a0 = p0[0], a1 = p0[64], a2 = p0[128];
        const fx4 b0 = p1[0], b1 = p1[64], b2 = p1[128];
        fx4 a3 = (fx4)0.f, b3 = (fx4)0.f;
        if (l < 4) { a3 = p0[192]; b3 = p1[192]; }

        float sa = (((a0.x + a0.y) + (a0.z + a0.w)) + ((a1.x + a1.y) + (a1.z + a1.w))) +
                   (((a2.x + a2.y) + (a2.z + a2.w)) + ((a3.x + a3.y) + (a3.z + a3.w)));
        float sb = (((b0.x + b0.y) + (b0.z + b0.w)) + ((b1.x + b1.y) + (b1.z + b1.w))) +
                   (((b2.x + b2.y) + (b2.z + b2.w)) + ((b3.x + b3.y) + (b3.z + b3.w)));
        #pragma unroll
        for (int off = 1; off < 64; off <<= 1) {
            sa += __shfl_xor(sa, off);
            sb += __shfl_xor(sb, off);
        }
        if (l == 0) {
            sums[g & 1][0][wv] = sa;
            sums[g & 1][1][wv] = sb;
        }
        __syncthreads();
        const float al0 = ((sums[g & 1][0][0] + sums[g & 1][0][1]) +
                           (sums[g & 1][0][2] + sums[g & 1][0][3])) * (1.0f / (float)HW);
        const float al1 = ((sums[g & 1][1][0] + sums[g & 1][1][1]) +
                           (sums[g & 1][1][2] + sums[g & 1][1][3])) * (1.0f / (float)HW);

        acc0 += a0 * al0 + b0 * al1;
        acc1 += a1 * al0 + b1 * al1;
        acc2 += a2 * al0 + b2 * al1;
        acc3 += a3 * al0 + b3 * al1;
    }

    // direct disjoint store of this wave's quarter (cached; B re-reads it)
    fx4* __restrict__ dst = (fx4*)(out + (size_t)b * C * HW + (size_t)pg * HW) + qbase + l;
    dst[0]   = acc0;
    dst[64]  = acc1;
    dst[128] = acc2;
    if (l < 4) dst[192] = acc3;
}

// ---------------------------------------------------------------------------
// Kernel B: sum 64 partials -> sal, then expansion (validated in R11).
// Block = (b, tile of 16 fx4 cols). Partials live in d_out planes co=0..63,
// read before this block overwrites them (read->sync->write within block).
// ---------------------------------------------------------------------------
__global__ __launch_bounds__(256) void out_kernel(const float* __restrict__ w,
                                                  const float* __restrict__ scale_p,
                                                  const float* __restrict__ wf_p,
                                                  float* __restrict__ out) {
    const int b    = blockIdx.y;
    const int tile = blockIdx.x;               // 0..48
    const int t    = threadIdx.x;
    const int hw4  = t & 15;
    const int pg4  = t >> 4;                   // 0..15 -> partials 4*pg4 .. 4*pg4+3
    const int lane = t & 63;
    const int wid  = t >> 6;

    const fx4* __restrict__ P =
        (const fx4*)(out + (size_t)b * C * HW) + tile * 16 + hw4;
    fx4 s = (P[(size_t)(4 * pg4) * HW4]     + P[(size_t)(4 * pg4 + 1) * HW4]) +
            (P[(size_t)(4 * pg4 + 2) * HW4] + P[(size_t)(4 * pg4 + 3) * HW4]);

    // reduce the 4 pg4-groups in this wave (lane deltas 16, 32)
    s.x += __shfl_xor(s.x, 16); s.y += __shfl_xor(s.y, 16);
    s.z += __shfl_xor(s.z, 16); s.w += __shfl_xor(s.w, 16);
    s.x += __shfl_xor(s.x, 32); s.y += __shfl_xor(s.y, 32);
    s.z += __shfl_xor(s.z, 32); s.w += __shfl_xor(s.w, 32);

    __shared__ fx4 red[4][16];
    if (lane < 16) red[wid][lane] = s;
    __syncthreads();

    __shared__ fx4 sal_sm[16];
    if (t < 16) {
        sal_sm[t] = ((red[0][t] + red[1][t]) + (red[2][t] + red[3][t])) *
                    (1.0f / (float)C);
    }
    __syncthreads();

    const float scale = scale_p[0];
    const float wf    = wf_p[0];
    const float out_zero = 1.0f - 0.5f * wf;   // fm == 0 path
    const fx4 s4 = sal_sm[hw4];

    fx4* __restrict__ ob = (fx4*)(out + (size_t)b * C * HW) + tile * 16 + hw4;
    const int c0 = pg4 * 32;                   // each group covers its 32 co's

    #pragma unroll 4
    for (int k = 0; k < 32; ++k) {
        const int co = c0 + k;
        const float wc = w[co];
        fx4 r;
        float fm;
        fm = s4.x * wc;
        r.x = (fm > TH) ? 1.0f - wf / (1.0f + __expf(-scale * fm)) : out_zero;
        fm = s4.y * wc;
        r.y = (fm > TH) ? 1.0f - wf / (1.0f + __expf(-scale * fm)) : out_zero;
        fm = s4.z * wc;
        r.z = (fm > TH) ? 1.0f - wf / (1.0f + __expf(-scale * fm)) : out_zero;
        fm = s4.w * wc;
        r.w = (fm > TH) ? 1.0f - wf / (1.0f + __expf(-scale * fm)) : out_zero;
        __builtin_nontemporal_store(r, ob + (size_t)co * HW4);
    }
}

extern "C" void kernel_launch(void* const* d_in, const int* in_sizes, int n_in,
                              void* d_out, int out_size, void* d_ws, size_t ws_size,
                              hipStream_t stream) {
    const float* x      = (const float*)d_in[0];
    const float* conv_w = (const float*)d_in[1];   // 512 floats
    const float* scale  = (const float*)d_in[2];
    const float* wf     = (const float*)d_in[3];
    float* out = (float*)d_out;

    dim3 gridA(NPG, B);                            // 64 x 32 = 2048 blocks
    partial_kernel<<<gridA, 256, 0, stream>>>(x, out);

    dim3 gridB(HW4 / 16, B);                       // 49 x 32 = 1568 blocks
    out_kernel<<<gridB, 256, 0, stream>>>(conv_w, scale, wf, out);
}